// Round 1
// baseline (225.771 us; speedup 1.0000x reference)
//
#include <hip/hip_runtime.h>
#include <stdint.h>

typedef __attribute__((ext_vector_type(8))) short short8;      // 8 bf16 (4 VGPRs)
typedef __attribute__((ext_vector_type(8))) unsigned short ushortx8;
typedef __attribute__((ext_vector_type(4))) float floatx4;     // MFMA C/D

#define MDIM 8192
#define KDIM 2048
#define NDIM 2048
#define BM 128
#define BN 128
#define BK 64

// async global->LDS, 16B per lane. LDS dest = wave-uniform base + lane*16.
__device__ __forceinline__ void load16_lds(const void* g, void* l) {
  __builtin_amdgcn_global_load_lds(
      (const __attribute__((address_space(1))) void*)g,
      (__attribute__((address_space(3))) void*)l, 16, 0, 0);
}

// ---- Phase 1a: binarize X (fp32 [M][K]) -> bf16 bits (ushort) [M][K] ----
__global__ void binarize_x_kernel(const float* __restrict__ X,
                                  unsigned short* __restrict__ Xb) {
  size_t i = ((size_t)blockIdx.x * 256 + threadIdx.x) * 8;
  const float4* xp = (const float4*)(X + i);
  float4 a = xp[0];
  float4 b = xp[1];
  ushortx8 o;
  o[0] = (a.x < 0.f) ? 0xBF80u : 0x3F80u;
  o[1] = (a.y < 0.f) ? 0xBF80u : 0x3F80u;
  o[2] = (a.z < 0.f) ? 0xBF80u : 0x3F80u;
  o[3] = (a.w < 0.f) ? 0xBF80u : 0x3F80u;
  o[4] = (b.x < 0.f) ? 0xBF80u : 0x3F80u;
  o[5] = (b.y < 0.f) ? 0xBF80u : 0x3F80u;
  o[6] = (b.z < 0.f) ? 0xBF80u : 0x3F80u;
  o[7] = (b.w < 0.f) ? 0xBF80u : 0x3F80u;
  *(ushortx8*)(Xb + i) = o;
}

// ---- Phase 1b: binarize + transpose W (fp32 [K][N]) -> bf16 bits [N][K] ----
__global__ void binarize_wT_kernel(const float* __restrict__ W,
                                   unsigned short* __restrict__ WbT) {
  __shared__ unsigned char t[64][65];  // +1 pad breaks bank conflicts
  const int n0 = blockIdx.x * 64;
  const int k0 = blockIdx.y * 64;
  const int c = threadIdx.x & 63;
  const int r0 = (threadIdx.x >> 6) * 16;
#pragma unroll
  for (int rr = 0; rr < 16; ++rr) {
    const int rk = r0 + rr;
    t[rk][c] = (W[(size_t)(k0 + rk) * NDIM + n0 + c] < 0.f) ? 1 : 0;
  }
  __syncthreads();
#pragma unroll
  for (int rr = 0; rr < 16; ++rr) {
    const int rn = r0 + rr;
    WbT[(size_t)(n0 + rn) * KDIM + k0 + c] = t[c][rn] ? 0xBF80u : 0x3F80u;
  }
}

// ---- Phase 2: m97-style bf16 MFMA GEMM: C[M][N] = A[M][K] * B[N][K]^T + bias ----
__global__ __launch_bounds__(256) void gemm_bin_bf16(
    const unsigned short* __restrict__ A,   // Xb  [M][K] bf16 bits
    const unsigned short* __restrict__ B,   // WbT [N][K] bf16 bits
    const float* __restrict__ bias,         // [N]
    float* __restrict__ C) {                // [M][N] fp32
  __shared__ __align__(16) unsigned short As[BM * BK];  // 16 KB
  __shared__ __align__(16) unsigned short Bs[BN * BK];  // 16 KB

  const int tid = threadIdx.x;
  const int lane = tid & 63;
  const int wv = tid >> 6;     // wave 0..3
  const int wm = wv >> 1;      // wave row 0..1 (64 rows each)
  const int wn = wv & 1;       // wave col 0..1
  const int r = lane & 15;     // MFMA m/n index
  const int q = lane >> 4;     // MFMA quad (k-group / row-group)

  const int m0 = blockIdx.x * BM;
  const int n0 = blockIdx.y * BN;

  floatx4 acc[4][4] = {};

  const int qbase = wv * 256;  // this wave's 16B-chunk range base

  for (int kb = 0; kb < KDIM; kb += BK) {
    // stage A-tile (128x64 bf16 = 16KB) and B-tile: 1024 chunks each, 4/thread
#pragma unroll
    for (int i = 0; i < 4; ++i) {
      const int qa = qbase + i * 64 + lane;     // linear chunk id
      const int row = qa >> 3;                  // tile row
      const int cc = qa & 7;                    // 16B chunk within row
      load16_lds(A + (size_t)(m0 + row) * KDIM + kb + cc * 8,
                 As + (size_t)(qbase + i * 64) * 8);
      load16_lds(B + (size_t)(n0 + row) * KDIM + kb + cc * 8,
                 Bs + (size_t)(qbase + i * 64) * 8);
    }
    __syncthreads();  // drains vmcnt (global_load_lds) before reads

#pragma unroll
    for (int s = 0; s < 2; ++s) {  // two k=32 substeps of the BK=64 tile
      short8 af[4], bf[4];
#pragma unroll
      for (int t = 0; t < 4; ++t) {
        // A frag: A[m = lane&15][k = q*8 + j]
        af[t] = *(const short8*)(As + (wm * 64 + t * 16 + r) * BK + s * 32 + q * 8);
        // B frag: B[k = q*8 + j][n = lane&15]  (Bs holds W^T rows = N)
        bf[t] = *(const short8*)(Bs + (wn * 64 + t * 16 + r) * BK + s * 32 + q * 8);
      }
#pragma unroll
      for (int tm = 0; tm < 4; ++tm)
#pragma unroll
        for (int tn = 0; tn < 4; ++tn)
          acc[tm][tn] = __builtin_amdgcn_mfma_f32_16x16x32_bf16(
              af[tm], bf[tn], acc[tm][tn], 0, 0, 0);
    }
    __syncthreads();  // protect LDS before next stage overwrites
  }

  // epilogue: C/D layout col=lane&15, row=q*4+v  (verified m89/m91)
#pragma unroll
  for (int tn = 0; tn < 4; ++tn) {
    const int col = n0 + wn * 64 + tn * 16 + r;
    const float bv = bias[col];
#pragma unroll
    for (int tm = 0; tm < 4; ++tm) {
      const int rowb = m0 + wm * 64 + tm * 16 + q * 4;
#pragma unroll
      for (int v = 0; v < 4; ++v)
        C[(size_t)(rowb + v) * NDIM + col] = acc[tm][tn][v] + bv;
    }
  }
}

extern "C" void kernel_launch(void* const* d_in, const int* in_sizes, int n_in,
                              void* d_out, int out_size, void* d_ws, size_t ws_size,
                              hipStream_t stream) {
  const float* X = (const float*)d_in[0];     // [8192, 2048]
  const float* W = (const float*)d_in[1];     // [2048, 2048]
  const float* bias = (const float*)d_in[2];  // [2048]
  float* out = (float*)d_out;

  unsigned short* Xb = (unsigned short*)d_ws;               // 32 MB
  unsigned short* WbT = Xb + (size_t)MDIM * KDIM;           // 8 MB  (ws total 40 MB)

  binarize_x_kernel<<<dim3((MDIM * KDIM) / (256 * 8)), 256, 0, stream>>>(X, Xb);
  binarize_wT_kernel<<<dim3(NDIM / 64, KDIM / 64), 256, 0, stream>>>(W, WbT);
  gemm_bin_bf16<<<dim3(MDIM / BM, NDIM / BN), 256, 0, stream>>>(Xb, WbT, bias, out);
}

// Round 2
// 208.933 us; speedup vs baseline: 1.0806x; 1.0806x over previous
//
#include <hip/hip_runtime.h>
#include <stdint.h>

typedef __attribute__((ext_vector_type(8))) short short8;      // 8 bf16 (4 VGPRs)
typedef __attribute__((ext_vector_type(8))) unsigned short ushortx8;
typedef __attribute__((ext_vector_type(4))) float floatx4;     // MFMA C/D

#define MDIM 8192
#define KDIM 2048
#define NDIM 2048
#define BM 128
#define BN 128
#define BK 64

// async global->LDS, 16B per lane. LDS dest = wave-uniform base + lane*16.
__device__ __forceinline__ void load16_lds(const void* g, void* l) {
  __builtin_amdgcn_global_load_lds(
      (const __attribute__((address_space(1))) void*)g,
      (__attribute__((address_space(3))) void*)l, 16, 0, 0);
}

// ---- Phase 1 (fused): binarize X row-major; binarize+transpose W ----
// blocks [0, XBLK): X -> Xb [M][K] bf16 bits, 16 elems/thread
// blocks [XBLK, XBLK+WBLK): W [K][N] -> WbT [N][K] bf16 bits
//   reads coalesced across lanes (same k, consecutive n); each thread owns
//   (n, 8 consecutive k) -> one 16B store; L2 write-combines the scatter.
#define XBLK 4096
#define WBLK 2048

__global__ void binarize_fused(const float* __restrict__ X,
                               const float* __restrict__ W,
                               unsigned short* __restrict__ Xb,
                               unsigned short* __restrict__ WbT) {
  const int b = blockIdx.x;
  if (b < XBLK) {
    size_t i = ((size_t)b * 256 + threadIdx.x) * 16;
    const float4* xp = (const float4*)(X + i);
#pragma unroll
    for (int h = 0; h < 2; ++h) {
      float4 a = xp[2 * h];
      float4 c = xp[2 * h + 1];
      ushortx8 o;
      o[0] = (a.x < 0.f) ? 0xBF80u : 0x3F80u;
      o[1] = (a.y < 0.f) ? 0xBF80u : 0x3F80u;
      o[2] = (a.z < 0.f) ? 0xBF80u : 0x3F80u;
      o[3] = (a.w < 0.f) ? 0xBF80u : 0x3F80u;
      o[4] = (c.x < 0.f) ? 0xBF80u : 0x3F80u;
      o[5] = (c.y < 0.f) ? 0xBF80u : 0x3F80u;
      o[6] = (c.z < 0.f) ? 0xBF80u : 0x3F80u;
      o[7] = (c.w < 0.f) ? 0xBF80u : 0x3F80u;
      *(ushortx8*)(Xb + i + h * 8) = o;
    }
  } else {
    const int bw = b - XBLK;
    const int nb = bw & 31;                       // n-block (64 wide)
    const int kb = bw >> 5;                       // k-chunk block (4 chunks)
    const int nn = threadIdx.x & 63;              // lane -> consecutive n
    const int kc = kb * 4 + (threadIdx.x >> 6);   // 8-k chunk id, 0..255
    const float* wp = W + (size_t)(kc * 8) * NDIM + nb * 64 + nn;
    ushortx8 o;
#pragma unroll
    for (int j = 0; j < 8; ++j)
      o[j] = (wp[(size_t)j * NDIM] < 0.f) ? 0xBF80u : 0x3F80u;
    *(ushortx8*)(WbT + (size_t)(nb * 64 + nn) * KDIM + kc * 8) = o;
  }
}

// ---- Phase 2: bf16 MFMA GEMM with XOR-swizzled LDS (conflict-free) ----
// C[M][N] = A[M][K] * B[N][K]^T + bias.
// LDS layout: row m's 16B chunk c stored at chunk (c ^ (m&7)); realized by
// permuting each lane's GLOBAL source chunk (stays in the same 128B row, so
// coalescing is preserved and the global_load_lds dest stays contiguous).
__global__ __launch_bounds__(256) void gemm_bin_bf16(
    const unsigned short* __restrict__ A,   // Xb  [M][K] bf16 bits
    const unsigned short* __restrict__ B,   // WbT [N][K] bf16 bits
    const float* __restrict__ bias,         // [N]
    float* __restrict__ C) {                // [M][N] fp32
  __shared__ __align__(16) unsigned short As[BM * BK];  // 16 KB
  __shared__ __align__(16) unsigned short Bs[BN * BK];  // 16 KB

  const int tid = threadIdx.x;
  const int lane = tid & 63;
  const int wv = tid >> 6;     // wave 0..3
  const int wm = wv >> 1;      // wave row (64 rows)
  const int wn = wv & 1;       // wave col (64 cols)
  const int r = lane & 15;     // MFMA m/n index
  const int q = lane >> 4;     // MFMA quad

  const int m0 = blockIdx.x * BM;
  const int n0 = blockIdx.y * BN;

  floatx4 acc[4][4] = {};

  const int qbase = wv * 256;  // this wave's 16B-chunk slot base

  // per-lane staging source offsets (slot -> swizzled global chunk)
  int srcoff[4];
#pragma unroll
  for (int i = 0; i < 4; ++i) {
    const int s = qbase + i * 64 + lane;
    const int row = s >> 3;
    const int cg = (s & 7) ^ (row & 7);   // global chunk for this LDS slot
    srcoff[i] = row * KDIM + cg * 8;
  }

  for (int kb = 0; kb < KDIM; kb += BK) {
#pragma unroll
    for (int i = 0; i < 4; ++i) {
      load16_lds(A + (size_t)m0 * KDIM + kb + srcoff[i],
                 As + (size_t)(qbase + i * 64) * 8);
      load16_lds(B + (size_t)n0 * KDIM + kb + srcoff[i],
                 Bs + (size_t)(qbase + i * 64) * 8);
    }
    __syncthreads();  // drains vmcnt (global_load_lds) before reads

#pragma unroll
    for (int s2 = 0; s2 < 2; ++s2) {  // two k=32 substeps
      const int cswz = (((s2 * 4 + q) ^ (r & 7)) * 8);  // swizzled chunk offset
      short8 af[4], bf[4];
#pragma unroll
      for (int t = 0; t < 4; ++t) {
        af[t] = *(const short8*)(As + (wm * 64 + t * 16 + r) * BK + cswz);
        bf[t] = *(const short8*)(Bs + (wn * 64 + t * 16 + r) * BK + cswz);
      }
#pragma unroll
      for (int tm = 0; tm < 4; ++tm)
#pragma unroll
        for (int tn = 0; tn < 4; ++tn)
          acc[tm][tn] = __builtin_amdgcn_mfma_f32_16x16x32_bf16(
              af[tm], bf[tn], acc[tm][tn], 0, 0, 0);
    }
    __syncthreads();
  }

  // epilogue: C/D layout col=lane&15, row=q*4+v (verified m89/m91; exact R1)
#pragma unroll
  for (int tn = 0; tn < 4; ++tn) {
    const int col = n0 + wn * 64 + tn * 16 + r;
    const float bv = bias[col];
#pragma unroll
    for (int tm = 0; tm < 4; ++tm) {
      const int rowb = m0 + wm * 64 + tm * 16 + q * 4;
#pragma unroll
      for (int v = 0; v < 4; ++v)
        C[(size_t)(rowb + v) * NDIM + col] = acc[tm][tn][v] + bv;
    }
  }
}

extern "C" void kernel_launch(void* const* d_in, const int* in_sizes, int n_in,
                              void* d_out, int out_size, void* d_ws, size_t ws_size,
                              hipStream_t stream) {
  const float* X = (const float*)d_in[0];     // [8192, 2048]
  const float* W = (const float*)d_in[1];     // [2048, 2048]
  const float* bias = (const float*)d_in[2];  // [2048]
  float* out = (float*)d_out;

  unsigned short* Xb = (unsigned short*)d_ws;               // 32 MB
  unsigned short* WbT = Xb + (size_t)MDIM * KDIM;           // 8 MB (ws 40 MB)

  binarize_fused<<<dim3(XBLK + WBLK), 256, 0, stream>>>(X, W, Xb, WbT);
  gemm_bin_bf16<<<dim3(MDIM / BM, NDIM / BN), 256, 0, stream>>>(Xb, WbT, bias, out);
}

// Round 3
// 167.949 us; speedup vs baseline: 1.3443x; 1.2440x over previous
//
#include <hip/hip_runtime.h>
#include <stdint.h>

typedef __attribute__((ext_vector_type(4))) int int4v;          // MFMA i8 A/B (16 i8) and i32 C/D
typedef __attribute__((ext_vector_type(16))) unsigned char uchar16;

#define MDIM 8192
#define KDIM 2048
#define NDIM 2048
#define BM 128
#define BN 128
#define BK 128   // i8 k per tile; rows are 128 B = 8 x 16B chunks (same chunk math as R2)

// async global->LDS, 16B per lane. LDS dest = wave-uniform base + lane*16.
__device__ __forceinline__ void load16_lds(const void* g, void* l) {
  __builtin_amdgcn_global_load_lds(
      (const __attribute__((address_space(1))) void*)g,
      (__attribute__((address_space(3))) void*)l, 16, 0, 0);
}

// ---- Phase 1 (fused): binarize X -> i8 [M][K]; binarize+transpose W -> i8 [N][K] ----
#define XBLK 4096   // M*K / (256*16)
#define WBLK 1024   // N*K / (256*16)

__global__ void binarize_fused(const float* __restrict__ X,
                               const float* __restrict__ W,
                               unsigned char* __restrict__ Xb,
                               unsigned char* __restrict__ WbT) {
  const int b = blockIdx.x;
  if (b < XBLK) {
    size_t i = ((size_t)b * 256 + threadIdx.x) * 16;
    const float4* xp = (const float4*)(X + i);
    uchar16 o;
#pragma unroll
    for (int h = 0; h < 4; ++h) {
      float4 a = xp[h];
      o[4 * h + 0] = (a.x < 0.f) ? 0xFFu : 0x01u;
      o[4 * h + 1] = (a.y < 0.f) ? 0xFFu : 0x01u;
      o[4 * h + 2] = (a.z < 0.f) ? 0xFFu : 0x01u;
      o[4 * h + 3] = (a.w < 0.f) ? 0xFFu : 0x01u;
    }
    *(uchar16*)(Xb + i) = o;
  } else {
    const int bw = b - XBLK;
    const int nb = bw & 31;                       // n-block (64 wide)
    const int kb = bw >> 5;                       // 64-k block
    const int nn = threadIdx.x & 63;              // lane -> consecutive n (coalesced reads)
    const int kc = kb * 4 + (threadIdx.x >> 6);   // 16-k chunk id, 0..127
    const float* wp = W + (size_t)(kc * 16) * NDIM + nb * 64 + nn;
    uchar16 o;
#pragma unroll
    for (int j = 0; j < 16; ++j)
      o[j] = (wp[(size_t)j * NDIM] < 0.f) ? 0xFFu : 0x01u;
    *(uchar16*)(WbT + (size_t)(nb * 64 + nn) * KDIM + kc * 16) = o;
  }
}

// ---- Phase 2: i8 MFMA GEMM with XOR-swizzled LDS (conflict-free, verified R2) ----
// C[M][N] = A[M][K] * B[N][K]^T + bias, exact integer accumulation in i32.
__global__ __launch_bounds__(256) void gemm_bin_i8(
    const unsigned char* __restrict__ A,    // Xb  [M][K] i8 (+1/-1)
    const unsigned char* __restrict__ B,    // WbT [N][K] i8 (+1/-1)
    const float* __restrict__ bias,         // [N]
    float* __restrict__ C) {                // [M][N] fp32
  __shared__ __align__(16) unsigned char As[BM * BK];  // 16 KB
  __shared__ __align__(16) unsigned char Bs[BN * BK];  // 16 KB

  const int tid = threadIdx.x;
  const int lane = tid & 63;
  const int wv = tid >> 6;     // wave 0..3
  const int wm = wv >> 1;      // wave row (64 rows)
  const int wn = wv & 1;       // wave col (64 cols)
  const int r = lane & 15;     // MFMA m/n index
  const int q = lane >> 4;     // MFMA quad

  const int m0 = blockIdx.x * BM;
  const int n0 = blockIdx.y * BN;

  int4v acc[4][4] = {};

  const int qbase = wv * 256;  // this wave's 16B-chunk slot base (1024 chunks/tile)

  // per-lane staging source offsets (slot -> XOR-swizzled global chunk, same row)
  int srcoff[4];
#pragma unroll
  for (int i = 0; i < 4; ++i) {
    const int s = qbase + i * 64 + lane;
    const int row = s >> 3;
    const int cg = (s & 7) ^ (row & 7);   // global 16B chunk for this LDS slot
    srcoff[i] = row * KDIM + cg * 16;     // bytes
  }

  for (int kb = 0; kb < KDIM; kb += BK) {
#pragma unroll
    for (int i = 0; i < 4; ++i) {
      load16_lds(A + (size_t)m0 * KDIM + kb + srcoff[i],
                 As + (size_t)(qbase + i * 64) * 16);
      load16_lds(B + (size_t)n0 * KDIM + kb + srcoff[i],
                 Bs + (size_t)(qbase + i * 64) * 16);
    }
    __syncthreads();  // drains vmcnt (global_load_lds) before reads

#pragma unroll
    for (int s2 = 0; s2 < 2; ++s2) {  // two k=64 substeps of BK=128
      const int cswz = ((s2 * 4 + q) ^ (r & 7)) * 16;  // swizzled chunk byte offset
      int4v af[4], bf[4];
#pragma unroll
      for (int t = 0; t < 4; ++t) {
        // A frag: A[m = lane&15][k = q*16 + j], j=0..15 (16 contiguous i8)
        af[t] = *(const int4v*)(As + (wm * 64 + t * 16 + r) * BK + cswz);
        bf[t] = *(const int4v*)(Bs + (wn * 64 + t * 16 + r) * BK + cswz);
      }
#pragma unroll
      for (int tm = 0; tm < 4; ++tm)
#pragma unroll
        for (int tn = 0; tn < 4; ++tn)
          acc[tm][tn] = __builtin_amdgcn_mfma_i32_16x16x64_i8(
              af[tm], bf[tn], acc[tm][tn], 0, 0, 0);
    }
    __syncthreads();
  }

  // epilogue: C/D layout col=lane&15, row=q*4+v (dtype-independent, m121-128)
#pragma unroll
  for (int tn = 0; tn < 4; ++tn) {
    const int col = n0 + wn * 64 + tn * 16 + r;
    const float bv = bias[col];
#pragma unroll
    for (int tm = 0; tm < 4; ++tm) {
      const int rowb = m0 + wm * 64 + tm * 16 + q * 4;
#pragma unroll
      for (int v = 0; v < 4; ++v)
        C[(size_t)(rowb + v) * NDIM + col] = (float)acc[tm][tn][v] + bv;
    }
  }
}

extern "C" void kernel_launch(void* const* d_in, const int* in_sizes, int n_in,
                              void* d_out, int out_size, void* d_ws, size_t ws_size,
                              hipStream_t stream) {
  const float* X = (const float*)d_in[0];     // [8192, 2048]
  const float* W = (const float*)d_in[1];     // [2048, 2048]
  const float* bias = (const float*)d_in[2];  // [2048]
  float* out = (float*)d_out;

  unsigned char* Xb = (unsigned char*)d_ws;                 // 16 MB
  unsigned char* WbT = Xb + (size_t)MDIM * KDIM;            // 4 MB (ws 20 MB)

  binarize_fused<<<dim3(XBLK + WBLK), 256, 0, stream>>>(X, W, Xb, WbT);
  gemm_bin_i8<<<dim3(MDIM / BM, NDIM / BN), 256, 0, stream>>>(Xb, WbT, bias, out);
}